// Round 1
// baseline (2935.267 us; speedup 1.0000x reference)
//
#include <hip/hip_runtime.h>
#include <cstdint>
#include <cstddef>

// Problem constants
#define NUM_C 4096
#define BB 32
#define TT 512
#define DD 128
#define MM 50

using ull = unsigned long long;

__device__ __forceinline__ float sigmoidf_(float x){ return 1.0f/(1.0f + expf(-x)); }

// ---------------------------------------------------------------------------
// Kernel A: parallel precompute.
//  - logits + softmax in fp64 (iv thresholds are discrete: need max accuracy)
//  - w_all (fp32) for the memory recurrence
//  - iv packed into 100-bit keys (2 bits per m) for exact match search
//  - fpre[b,t,d] = k_t . f_W[d,128:256] + f_b[d]
//  - ypre[b,t,d] = a_W[d,q]*r + a_b[d]
// Grid: (16 t-chunks, 32 batches), 256 threads. LDS ~55KB.
// ---------------------------------------------------------------------------
__global__ __launch_bounds__(256) void kPre(
    const int* __restrict__ q, const int* __restrict__ r,
    const float* __restrict__ k_emb, const float* __restrict__ Mk,
    const float* __restrict__ f_W, const float* __restrict__ f_b,
    const float* __restrict__ a_W, const float* __restrict__ a_b,
    float* __restrict__ wAll, ull* __restrict__ keyLo, ull* __restrict__ keyHi,
    float* __restrict__ fpre, float* __restrict__ ypre)
{
  const int b = blockIdx.y, t0 = blockIdx.x * 32, tid = threadIdx.x;
  __shared__ __align__(16) float sK[32*129];   // k rows, padded (bank-spread)
  __shared__ int sQ[32];
  __shared__ int sR[32];
  __shared__ union UU {
    struct { float sMk[MM*129]; double sZ[32*MM]; } p2;  // logits phase
    float sW2[128*65];                                    // fpre phase (half of f_W2)
  } u;

  if (tid < 32){ sQ[tid] = q[b*TT + t0 + tid]; sR[tid] = r[b*TT + t0 + tid]; }
  __syncthreads();
  for (int i = tid; i < 32*128; i += 256){
    int tl = i >> 7, j = i & 127;
    sK[tl*129 + j] = k_emb[(size_t)sQ[tl]*DD + j];
  }
  for (int i = tid; i < MM*128; i += 256){
    int m = i >> 7, j = i & 127;
    u.p2.sMk[m*129 + j] = Mk[i];
  }
  __syncthreads();

  // logits in fp64
  for (int idx = tid; idx < 32*MM; idx += 256){
    int tl = idx / MM, m = idx - tl*MM;
    double z = 0.0;
    for (int j = 0; j < DD; j++)
      z += (double)sK[tl*129 + j] * (double)u.p2.sMk[m*129 + j];
    u.p2.sZ[tl*MM + m] = z;
  }
  __syncthreads();

  // softmax + iv keys: 8 lanes per (b,t) row
  {
    int tl = tid >> 3, l8 = tid & 7;
    double zmax = -1e300;
    for (int m = l8; m < MM; m += 8) zmax = fmax(zmax, u.p2.sZ[tl*MM + m]);
    for (int s = 1; s < 8; s <<= 1) zmax = fmax(zmax, __shfl_xor(zmax, s));
    double se = 0.0;
    for (int m = l8; m < MM; m += 8){
      double e = exp(u.p2.sZ[tl*MM + m] - zmax);
      u.p2.sZ[tl*MM + m] = e;
      se += e;
    }
    for (int s = 1; s < 8; s <<= 1) se += __shfl_xor(se, s);
    double inv = 1.0 / se;
    ull klo = 0, khi = 0;
    for (int m = l8; m < MM; m += 8){
      double w = u.p2.sZ[tl*MM + m] * inv;
      wAll[((size_t)(b*TT + t0 + tl))*MM + m] = (float)w;
      // triangular membership + quantize (python-double constants)
      double tw = fmin((w - 0.075)/(0.088 - 0.075), (1.0 - w)/(1.0 - 0.088));
      tw = fmax(tw, 0.0);
      ull iv = (tw >= 0.6) ? 2ull : ((tw >= 0.1) ? 1ull : 0ull);
      if (m < 32) klo |= iv << (2*m); else khi |= iv << (2*(m-32));
    }
    for (int s = 1; s < 8; s <<= 1){ klo |= __shfl_xor(klo, s); khi |= __shfl_xor(khi, s); }
    if (l8 == 0){ keyLo[b*TT + t0 + tl] = klo; keyHi[b*TT + t0 + tl] = khi; }
  }

  // fpre: 4x4 register tiles, two 64-wide j halves through the LDS union
  {
    const int dq = tid & 31, tq = tid >> 5;
    float acc[4][4];
    #pragma unroll
    for (int a = 0; a < 4; a++){ acc[a][0]=0.f; acc[a][1]=0.f; acc[a][2]=0.f; acc[a][3]=0.f; }
    for (int jh = 0; jh < 2; jh++){
      __syncthreads();  // union reuse guard (softmax done / prev pass reads done)
      for (int i = tid; i < 128*64; i += 256){
        int dd = i >> 6, jj = i & 63;
        u.sW2[dd*65 + jj] = f_W[dd*256 + 128 + jh*64 + jj];
      }
      __syncthreads();
      for (int jj = 0; jj < 64; jj++){
        float kv[4], wv[4];
        #pragma unroll
        for (int a = 0; a < 4; a++) kv[a] = sK[(tq*4 + a)*129 + jh*64 + jj];
        #pragma unroll
        for (int c = 0; c < 4; c++) wv[c] = u.sW2[(dq*4 + c)*65 + jj];
        #pragma unroll
        for (int a = 0; a < 4; a++){
          acc[a][0] += kv[a]*wv[0]; acc[a][1] += kv[a]*wv[1];
          acc[a][2] += kv[a]*wv[2]; acc[a][3] += kv[a]*wv[3];
        }
      }
    }
    #pragma unroll
    for (int a = 0; a < 4; a++){
      int tl = tq*4 + a;
      #pragma unroll
      for (int c = 0; c < 4; c++){
        int d = dq*4 + c;
        fpre[((size_t)(b*TT + t0 + tl))*DD + d] = acc[a][c] + f_b[d];
      }
    }
  }

  // ypre = a_W[d, q]*r + a_b[d]  (scattered a_W column gather, L2-resident)
  for (int i = tid; i < 32*DD; i += 256){
    int tl = i >> 7, d = i & 127;
    ypre[((size_t)(b*TT + t0 + tl))*DD + d] =
        a_W[(size_t)d*(NUM_C + DD) + sQ[tl]] * (float)sR[tl] + a_b[d];
  }
}

// ---------------------------------------------------------------------------
// Kernel A2: exact match search. For each (b,i): latest j<i with identical
// iv row (dist==0 exactly). prev=-1 means unmatched. 32 blocks x 512 threads.
// ---------------------------------------------------------------------------
__global__ __launch_bounds__(512) void kMatch(
    const ull* __restrict__ keyLo, const ull* __restrict__ keyHi, int* __restrict__ prevA)
{
  const int b = blockIdx.x, i = threadIdx.x;
  __shared__ ull slo[TT];
  __shared__ ull shi[TT];
  slo[i] = keyLo[b*TT + i];
  shi[i] = keyHi[b*TT + i];
  __syncthreads();
  const ull mylo = slo[i], myhi = shi[i];
  int found = -1;
  for (int j = i - 1; j >= 0; j--){
    if (slo[j] == mylo && shi[j] == myhi){ found = j; break; }
  }
  prevA[b*TT + i] = found;
}

// ---------------------------------------------------------------------------
// Kernel B: memory recurrence (the sequential core). One block per batch,
// 512 threads (8 waves). The four DxD weight matrices live in REGISTERS
// (128 floats/thread); activations broadcast via LDS (wave-uniform address
// -> conflict-free broadcast). Mv state in LDS (25.6KB).
// ---------------------------------------------------------------------------
__global__ __launch_bounds__(512, 2) void kMem(
    const float* __restrict__ wAll, const float* __restrict__ fpre, const float* __restrict__ ypre,
    const float* __restrict__ f_W, const float* __restrict__ a_W,
    const float* __restrict__ e_W, const float* __restrict__ e_b,
    const float* __restrict__ add_W, const float* __restrict__ add_b,
    const float* __restrict__ Mv0, float* __restrict__ fAll)
{
  const int b = blockIdx.x, tid = threadIdx.x;
  const int d = tid & 127, kb = tid >> 7;   // kb uniform per wave -> LDS broadcasts
  float wf[32], wa[32], we[32], wd[32];
  #pragma unroll
  for (int i = 0; i < 32; i++){
    wf[i] = f_W[d*256 + kb*32 + i];                          // f_W[d, 0:128]
    wa[i] = a_W[(size_t)d*(NUM_C + DD) + NUM_C + kb*32 + i]; // a_Wf[d, :]
    we[i] = e_W[d*DD + kb*32 + i];
    wd[i] = add_W[d*DD + kb*32 + i];
  }
  __shared__ __align__(16) float sMv[MM*DD];
  __shared__ __align__(16) float sx[DD];
  __shared__ float sw[64];
  __shared__ float part[1024];
  __shared__ float se_[DD];
  __shared__ float sa_[DD];
  for (int i = tid; i < MM*DD; i += 512) sMv[i] = Mv0[i];
  const float ebv = e_b[d], adbv = add_b[d];
  float fpre_c = 0.f, ypre_c = 0.f;
  if (tid < DD){
    fpre_c = fpre[((size_t)b*TT)*DD + tid];
    ypre_c = ypre[((size_t)b*TT)*DD + tid];
  }
  __syncthreads();

  for (int t = 0; t < TT; t++){
    const size_t row = (size_t)b*TT + t;
    if (tid < MM) sw[tid] = wAll[row*MM + tid];
    float fpre_n = 0.f, ypre_n = 0.f;
    if (tid < DD && t + 1 < TT){            // prefetch next step (hidden under this step)
      fpre_n = fpre[(row + 1)*DD + tid];
      ypre_n = ypre[(row + 1)*DD + tid];
    }
    __syncthreads();

    // stage 1: read[d] = sum_m w[m] * Mv[m][d]
    {
      float a0 = 0.f;
      int m0 = kb*13, m1 = m0 + 13; if (m1 > MM) m1 = MM;
      for (int m = m0; m < m1; m++) a0 += sw[m]*sMv[m*DD + d];
      part[tid] = a0;
    }
    __syncthreads();
    if (tid < DD) sx[tid] = part[tid] + part[tid+128] + part[tid+256] + part[tid+384];
    __syncthreads();

    // stage 2: f = tanh(read @ f_Wr.T + fpre)
    {
      const float4* x4 = reinterpret_cast<const float4*>(sx + kb*32);
      float a0=0.f,a1=0.f,a2=0.f,a3=0.f;
      #pragma unroll
      for (int i = 0; i < 8; i++){
        float4 xv = x4[i];
        a0 += xv.x*wf[4*i]; a1 += xv.y*wf[4*i+1]; a2 += xv.z*wf[4*i+2]; a3 += xv.w*wf[4*i+3];
      }
      part[tid] = (a0+a1)+(a2+a3);
    }
    __syncthreads();
    if (tid < DD){
      float v = part[tid] + part[tid+128] + part[tid+256] + part[tid+384] + fpre_c;
      float f = tanhf(v);
      sx[tid] = f;
      fAll[row*DD + tid] = f;
    }
    __syncthreads();

    // stage 3: y = ypre + f @ a_Wf.T
    {
      const float4* x4 = reinterpret_cast<const float4*>(sx + kb*32);
      float a0=0.f,a1=0.f,a2=0.f,a3=0.f;
      #pragma unroll
      for (int i = 0; i < 8; i++){
        float4 xv = x4[i];
        a0 += xv.x*wa[4*i]; a1 += xv.y*wa[4*i+1]; a2 += xv.z*wa[4*i+2]; a3 += xv.w*wa[4*i+3];
      }
      part[tid] = (a0+a1)+(a2+a3);
    }
    __syncthreads();
    if (tid < DD) sx[tid] = part[tid] + part[tid+128] + part[tid+256] + part[tid+384] + ypre_c;
    __syncthreads();

    // stage 4: e = sigmoid(y@e_W.T), a = tanh(y@add_W.T)
    {
      const float4* x4 = reinterpret_cast<const float4*>(sx + kb*32);
      float e0=0.f,e1=0.f,g0=0.f,g1=0.f;
      #pragma unroll
      for (int i = 0; i < 8; i++){
        float4 xv = x4[i];
        e0 += xv.x*we[4*i];   e1 += xv.y*we[4*i+1];
        e0 += xv.z*we[4*i+2]; e1 += xv.w*we[4*i+3];
        g0 += xv.x*wd[4*i];   g1 += xv.y*wd[4*i+1];
        g0 += xv.z*wd[4*i+2]; g1 += xv.w*wd[4*i+3];
      }
      part[tid] = e0 + e1;
      part[512 + tid] = g0 + g1;
    }
    __syncthreads();
    if (tid < DD){
      float ev = part[tid] + part[tid+128] + part[tid+256] + part[tid+384] + ebv;
      float av = part[512+tid] + part[512+tid+128] + part[512+tid+256] + part[512+tid+384] + adbv;
      se_[tid] = sigmoidf_(ev);
      sa_[tid] = tanhf(av);
    }
    __syncthreads();

    // stage 5: Mv = Mv*(1 - w e^T) + w a^T
    for (int i = tid; i < MM*DD; i += 512){
      int m = i >> 7, dd2 = i & 127;
      float w = sw[m];
      sMv[i] = sMv[i]*(1.f - w*se_[dd2]) + w*sa_[dd2];
    }
    fpre_c = fpre_n; ypre_c = ypre_n;
    __syncthreads();
  }
}

// ---------------------------------------------------------------------------
// Kernel D: gpre[b,t,j] = f_all[b,t,:] . Wih[j,:] + bih[j] + bhh[j]
// Tiled fp32 GEMM: 32-row x 64-j tiles. Grid (8, 512), 256 threads.
// ---------------------------------------------------------------------------
__global__ __launch_bounds__(256) void kGate(
    const float* __restrict__ fAll, const float* __restrict__ Wih,
    const float* __restrict__ bih, const float* __restrict__ bhh,
    float* __restrict__ gpre)
{
  const int jt = blockIdx.x;   // 8 tiles of 64 j
  const int rt = blockIdx.y;   // 512 tiles of 32 rows
  const int tid = threadIdx.x;
  __shared__ float sW[64*129];
  __shared__ float sF[32*129];
  for (int i = tid; i < 64*128; i += 256){
    int jj = i >> 7, k = i & 127;
    sW[jj*129 + k] = Wih[(size_t)(jt*64 + jj)*128 + k];
  }
  for (int i = tid; i < 32*128; i += 256){
    int rr = i >> 7, k = i & 127;
    sF[rr*129 + k] = fAll[(size_t)(rt*32 + rr)*128 + k];
  }
  __syncthreads();
  const int jq = tid & 31, rq = tid >> 5;
  float acc[4][2];
  #pragma unroll
  for (int a = 0; a < 4; a++){ acc[a][0] = 0.f; acc[a][1] = 0.f; }
  for (int k = 0; k < 128; k++){
    float fv[4], wv[2];
    #pragma unroll
    for (int a = 0; a < 4; a++) fv[a] = sF[(rq*4 + a)*129 + k];
    wv[0] = sW[(jq*2 + 0)*129 + k];
    wv[1] = sW[(jq*2 + 1)*129 + k];
    #pragma unroll
    for (int a = 0; a < 4; a++){ acc[a][0] += fv[a]*wv[0]; acc[a][1] += fv[a]*wv[1]; }
  }
  #pragma unroll
  for (int a = 0; a < 4; a++){
    int rowi = rt*32 + rq*4 + a;
    #pragma unroll
    for (int c = 0; c < 2; c++){
      int j = jt*64 + jq*2 + c;
      gpre[(size_t)rowi*512 + j] = acc[a][c] + bih[j] + bhh[j];
    }
  }
}

// ---------------------------------------------------------------------------
// Kernel C: LSTM with skip routing. One block per batch, 512 threads.
// Whh row j (128 floats) lives in thread j's registers. H/C histories in
// global ws (read back only by the SAME thread that wrote -> trivially safe).
// ---------------------------------------------------------------------------
__global__ __launch_bounds__(512, 2) void kLstm(
    const float* __restrict__ gpre, const int* __restrict__ prevA,
    const float* __restrict__ Whh, const float* __restrict__ p_W, const float* __restrict__ p_b,
    float* __restrict__ Hh, float* __restrict__ Ch, float* __restrict__ out)
{
  const int b = blockIdx.x, j = threadIdx.x;
  float whh[128];
  #pragma unroll
  for (int i = 0; i < 128; i++) whh[i] = Whh[(size_t)j*128 + i];
  __shared__ __align__(16) float xh[DD];
  __shared__ float sg[512];
  __shared__ float sh[DD];
  __shared__ float sc[DD];
  __shared__ float pred[DD];
  if (j < DD){ sh[j] = 0.f; sc[j] = 0.f; }
  const float pwv = (j < DD) ? p_W[j] : 0.f;
  const float pbv = p_b[0];
  float g_c = gpre[((size_t)b*TT)*512 + j];
  int pv_c = prevA[b*TT];   // always -1 at t=0
  __syncthreads();

  for (int t = 0; t < TT; t++){
    const size_t row = (size_t)b*TT + t;
    float g_n = 0.f; int pv_n = 0;
    if (t + 1 < TT){ g_n = gpre[(row + 1)*512 + j]; pv_n = prevA[row + 1]; }

    float cin = 0.f;
    if (j < DD){
      float hin;
      if (pv_c >= 0){
        hin = Hh[((size_t)b*TT + pv_c)*DD + j];
        cin = Ch[((size_t)b*TT + pv_c)*DD + j];
      } else {
        hin = sh[j]; cin = sc[j];
      }
      xh[j] = hin;
    }
    __syncthreads();

    // gates[j] = gpre + h_in . Whh[j,:]
    {
      const float4* x4 = reinterpret_cast<const float4*>(xh);
      float a0=0.f,a1=0.f,a2=0.f,a3=0.f;
      #pragma unroll
      for (int i = 0; i < 32; i++){
        float4 xv = x4[i];
        a0 += xv.x*whh[4*i]; a1 += xv.y*whh[4*i+1]; a2 += xv.z*whh[4*i+2]; a3 += xv.w*whh[4*i+3];
      }
      sg[j] = g_c + (a0+a1)+(a2+a3);
    }
    __syncthreads();

    if (j < DD){
      float ig = sg[j], fg = sg[DD + j], gg = sg[2*DD + j], og = sg[3*DD + j];
      float cn = sigmoidf_(fg)*cin + sigmoidf_(ig)*tanhf(gg);
      float hn = sigmoidf_(og)*tanhf(cn);
      sh[j] = hn; sc[j] = cn;
      Hh[row*DD + j] = hn;
      Ch[row*DD + j] = cn;
      pred[j] = hn*pwv;
    }
    __syncthreads();

    if (j < 64){
      float s = pred[j] + pred[j + 64];
      s += __shfl_down(s, 32); s += __shfl_down(s, 16); s += __shfl_down(s, 8);
      s += __shfl_down(s, 4);  s += __shfl_down(s, 2);  s += __shfl_down(s, 1);
      if (j == 0) out[row] = sigmoidf_(s + pbv);
    }
    g_c = g_n; pv_c = pv_n;
  }
}

// ---------------------------------------------------------------------------
// Launch. Workspace layout (~75.5 MiB total; all regions written before read):
// ---------------------------------------------------------------------------
extern "C" void kernel_launch(void* const* d_in, const int* in_sizes, int n_in,
                              void* d_out, int out_size, void* d_ws, size_t ws_size,
                              hipStream_t stream) {
  const int*   q     = (const int*)  d_in[0];
  const int*   r     = (const int*)  d_in[1];
  const float* k_emb = (const float*)d_in[2];
  const float* Mk    = (const float*)d_in[3];
  const float* Mv0   = (const float*)d_in[4];
  const float* f_W   = (const float*)d_in[5];
  const float* f_b   = (const float*)d_in[6];
  const float* a_W   = (const float*)d_in[7];
  const float* a_b   = (const float*)d_in[8];
  const float* e_W   = (const float*)d_in[9];
  const float* e_b   = (const float*)d_in[10];
  const float* add_W = (const float*)d_in[11];
  const float* add_b = (const float*)d_in[12];
  const float* Wih   = (const float*)d_in[13];
  const float* Whh   = (const float*)d_in[14];
  const float* bih   = (const float*)d_in[15];
  const float* bhh   = (const float*)d_in[16];
  const float* p_W   = (const float*)d_in[17];
  const float* p_b   = (const float*)d_in[18];
  float* out = (float*)d_out;

  char* ws = (char*)d_ws;
  size_t off = 0;
  auto alloc = [&](size_t bytes) -> char* {
    char* p = ws + off;
    off += (bytes + 255) & ~(size_t)255;
    return p;
  };
  float* wAll  = (float*)alloc((size_t)BB*TT*MM*4);      // 3.28 MB
  float* fpre  = (float*)alloc((size_t)BB*TT*DD*4);      // 8.39 MB
  float* ypre  = (float*)alloc((size_t)BB*TT*DD*4);      // 8.39 MB
  float* fAll  = (float*)alloc((size_t)BB*TT*DD*4);      // 8.39 MB
  float* gpre  = (float*)alloc((size_t)BB*TT*512*4);     // 33.6 MB
  float* Hh    = (float*)alloc((size_t)BB*TT*DD*4);      // 8.39 MB
  float* Ch    = (float*)alloc((size_t)BB*TT*DD*4);      // 8.39 MB
  ull*   keyLo = (ull*)  alloc((size_t)BB*TT*8);
  ull*   keyHi = (ull*)  alloc((size_t)BB*TT*8);
  int*   prevA = (int*)  alloc((size_t)BB*TT*4);
  (void)ws_size; (void)in_sizes; (void)n_in; (void)out_size;

  kPre  <<<dim3(16, 32), 256, 0, stream>>>(q, r, k_emb, Mk, f_W, f_b, a_W, a_b,
                                           wAll, keyLo, keyHi, fpre, ypre);
  kMatch<<<32, 512, 0, stream>>>(keyLo, keyHi, prevA);
  kMem  <<<32, 512, 0, stream>>>(wAll, fpre, ypre, f_W, a_W, e_W, e_b, add_W, add_b,
                                 Mv0, fAll);
  kGate <<<dim3(8, 512), 256, 0, stream>>>(fAll, Wih, bih, bhh, gpre);
  kLstm <<<32, 512, 0, stream>>>(gpre, prevA, Whh, p_W, p_b, Hh, Ch, out);
}

// Round 2
// 2181.843 us; speedup vs baseline: 1.3453x; 1.3453x over previous
//
#include <hip/hip_runtime.h>
#include <cstdint>
#include <cstddef>

// Problem constants
#define NUM_C 4096
#define BB 32
#define TT 512
#define DD 128
#define MM 50

using ull = unsigned long long;

__device__ __forceinline__ float sigmoidf_(float x){ return 1.0f/(1.0f + expf(-x)); }

// ---------------------------------------------------------------------------
// Kernel A: parallel precompute (unchanged from R0).
// ---------------------------------------------------------------------------
__global__ __launch_bounds__(256) void kPre(
    const int* __restrict__ q, const int* __restrict__ r,
    const float* __restrict__ k_emb, const float* __restrict__ Mk,
    const float* __restrict__ f_W, const float* __restrict__ f_b,
    const float* __restrict__ a_W, const float* __restrict__ a_b,
    float* __restrict__ wAll, ull* __restrict__ keyLo, ull* __restrict__ keyHi,
    float* __restrict__ fpre, float* __restrict__ ypre)
{
  const int b = blockIdx.y, t0 = blockIdx.x * 32, tid = threadIdx.x;
  __shared__ __align__(16) float sK[32*129];
  __shared__ int sQ[32];
  __shared__ int sR[32];
  __shared__ union UU {
    struct { float sMk[MM*129]; double sZ[32*MM]; } p2;
    float sW2[128*65];
  } u;

  if (tid < 32){ sQ[tid] = q[b*TT + t0 + tid]; sR[tid] = r[b*TT + t0 + tid]; }
  __syncthreads();
  for (int i = tid; i < 32*128; i += 256){
    int tl = i >> 7, j = i & 127;
    sK[tl*129 + j] = k_emb[(size_t)sQ[tl]*DD + j];
  }
  for (int i = tid; i < MM*128; i += 256){
    int m = i >> 7, j = i & 127;
    u.p2.sMk[m*129 + j] = Mk[i];
  }
  __syncthreads();

  for (int idx = tid; idx < 32*MM; idx += 256){
    int tl = idx / MM, m = idx - tl*MM;
    double z = 0.0;
    for (int j = 0; j < DD; j++)
      z += (double)sK[tl*129 + j] * (double)u.p2.sMk[m*129 + j];
    u.p2.sZ[tl*MM + m] = z;
  }
  __syncthreads();

  {
    int tl = tid >> 3, l8 = tid & 7;
    double zmax = -1e300;
    for (int m = l8; m < MM; m += 8) zmax = fmax(zmax, u.p2.sZ[tl*MM + m]);
    for (int s = 1; s < 8; s <<= 1) zmax = fmax(zmax, __shfl_xor(zmax, s));
    double se = 0.0;
    for (int m = l8; m < MM; m += 8){
      double e = exp(u.p2.sZ[tl*MM + m] - zmax);
      u.p2.sZ[tl*MM + m] = e;
      se += e;
    }
    for (int s = 1; s < 8; s <<= 1) se += __shfl_xor(se, s);
    double inv = 1.0 / se;
    ull klo = 0, khi = 0;
    for (int m = l8; m < MM; m += 8){
      double w = u.p2.sZ[tl*MM + m] * inv;
      wAll[((size_t)(b*TT + t0 + tl))*MM + m] = (float)w;
      double tw = fmin((w - 0.075)/(0.088 - 0.075), (1.0 - w)/(1.0 - 0.088));
      tw = fmax(tw, 0.0);
      ull iv = (tw >= 0.6) ? 2ull : ((tw >= 0.1) ? 1ull : 0ull);
      if (m < 32) klo |= iv << (2*m); else khi |= iv << (2*(m-32));
    }
    for (int s = 1; s < 8; s <<= 1){ klo |= __shfl_xor(klo, s); khi |= __shfl_xor(khi, s); }
    if (l8 == 0){ keyLo[b*TT + t0 + tl] = klo; keyHi[b*TT + t0 + tl] = khi; }
  }

  {
    const int dq = tid & 31, tq = tid >> 5;
    float acc[4][4];
    #pragma unroll
    for (int a = 0; a < 4; a++){ acc[a][0]=0.f; acc[a][1]=0.f; acc[a][2]=0.f; acc[a][3]=0.f; }
    for (int jh = 0; jh < 2; jh++){
      __syncthreads();
      for (int i = tid; i < 128*64; i += 256){
        int dd = i >> 6, jj = i & 63;
        u.sW2[dd*65 + jj] = f_W[dd*256 + 128 + jh*64 + jj];
      }
      __syncthreads();
      for (int jj = 0; jj < 64; jj++){
        float kv[4], wv[4];
        #pragma unroll
        for (int a = 0; a < 4; a++) kv[a] = sK[(tq*4 + a)*129 + jh*64 + jj];
        #pragma unroll
        for (int c = 0; c < 4; c++) wv[c] = u.sW2[(dq*4 + c)*65 + jj];
        #pragma unroll
        for (int a = 0; a < 4; a++){
          acc[a][0] += kv[a]*wv[0]; acc[a][1] += kv[a]*wv[1];
          acc[a][2] += kv[a]*wv[2]; acc[a][3] += kv[a]*wv[3];
        }
      }
    }
    #pragma unroll
    for (int a = 0; a < 4; a++){
      int tl = tq*4 + a;
      #pragma unroll
      for (int c = 0; c < 4; c++){
        int d = dq*4 + c;
        fpre[((size_t)(b*TT + t0 + tl))*DD + d] = acc[a][c] + f_b[d];
      }
    }
  }

  for (int i = tid; i < 32*DD; i += 256){
    int tl = i >> 7, d = i & 127;
    ypre[((size_t)(b*TT + t0 + tl))*DD + d] =
        a_W[(size_t)d*(NUM_C + DD) + sQ[tl]] * (float)sR[tl] + a_b[d];
  }
}

// ---------------------------------------------------------------------------
// Kernel A2: exact match search (unchanged).
// ---------------------------------------------------------------------------
__global__ __launch_bounds__(512) void kMatch(
    const ull* __restrict__ keyLo, const ull* __restrict__ keyHi, int* __restrict__ prevA)
{
  const int b = blockIdx.x, i = threadIdx.x;
  __shared__ ull slo[TT];
  __shared__ ull shi[TT];
  slo[i] = keyLo[b*TT + i];
  shi[i] = keyHi[b*TT + i];
  __syncthreads();
  const ull mylo = slo[i], myhi = shi[i];
  int found = -1;
  for (int j = i - 1; j >= 0; j--){
    if (slo[j] == mylo && shi[j] == myhi){ found = j; break; }
  }
  prevA[b*TT + i] = found;
}

// ---------------------------------------------------------------------------
// Kernel B (REWRITTEN): memory recurrence, wave-local reductions.
// One block/batch, 512 threads (8 waves). Lane layout:
//   w = tid>>6, l = tid&63;  d = 16*w + (l&15);  kc = l>>4 (0..3)
// Thread owns: Mv[m in 13-chunk kc][d] in registers (stage-1 read & stage-5
// update are register-only, NO barrier), weight slices W[d][kc*32..+32] of
// the four DxD matrices, and prefetched wAll/fpre/ypre for t+1.
// Per step: 3 barriers (vs 10 in R0). Reductions: 2x __shfl_xor (16,32).
// LDS: 3 rotating 4x36-padded activation buffers (conflict-free b128 reads).
// ---------------------------------------------------------------------------
__global__ __launch_bounds__(512, 2) void kMem(
    const float* __restrict__ wAll, const float* __restrict__ fpre, const float* __restrict__ ypre,
    const float* __restrict__ f_W, const float* __restrict__ a_W,
    const float* __restrict__ e_W, const float* __restrict__ e_b,
    const float* __restrict__ add_W, const float* __restrict__ add_b,
    const float* __restrict__ Mv0, float* __restrict__ fAll)
{
  const int b = blockIdx.x, tid = threadIdx.x;
  const int w = tid >> 6, l = tid & 63;
  const int d = w*16 + (l & 15);
  const int kc = l >> 4;                 // 0..3
  const int m0 = kc*13;                  // m-chunk base (13,13,13,11)
  const int slice = w >> 1;              // which 32-slice of [0,128) this wave's d's live in
  const int dIn = (w & 1)*16 + (l & 15); // d & 31

  // ---- register-resident state & weights ----
  float mv[13];
  #pragma unroll
  for (int i = 0; i < 13; i++){
    int m = m0 + i;
    mv[i] = (m < MM) ? Mv0[(size_t)m*DD + d] : 0.f;
  }
  float wf[32], wa[32], we[32], wd[32];
  #pragma unroll
  for (int i = 0; i < 32; i++){
    wf[i] = f_W[d*256 + kc*32 + i];                          // f_W[d, 0:128] (read part)
    wa[i] = a_W[(size_t)d*(NUM_C + DD) + NUM_C + kc*32 + i]; // a_Wf[d, :]
    we[i] = e_W[d*DD + kc*32 + i];
    wd[i] = add_W[d*DD + kc*32 + i];
  }
  const float ebv = e_b[d], adbv = add_b[d];

  __shared__ __align__(16) float bufR[4*36];
  __shared__ __align__(16) float bufF[4*36];
  __shared__ __align__(16) float bufY[4*36];

  // ---- t=0 operand load + persistent prefetch registers ----
  const size_t base = (size_t)b*TT;
  float w_cur[13], w_nxt[13];
  #pragma unroll
  for (int i = 0; i < 13; i++){
    int m = m0 + i; if (m > MM-1) m = MM-1;
    w_cur[i] = wAll[base*MM + m];
  }
  float fpre_c = fpre[base*DD + d];
  float ypre_c = ypre[base*DD + d];
  __syncthreads();

  for (int t = 0; t < TT; t++){
    const size_t row = base + t;
    const size_t rowN = (t + 1 < TT) ? row + 1 : row;

    // issue t+1 prefetches (drain at barriers; off critical path)
    #pragma unroll
    for (int i = 0; i < 13; i++){
      int m = m0 + i; if (m > MM-1) m = MM-1;
      w_nxt[i] = wAll[rowN*MM + m];
    }
    float fpre_n = fpre[rowN*DD + d];
    float ypre_n = ypre[rowN*DD + d];

    // ---- stage 1: read[d] = sum_m w[m]*Mv[m][d]  (registers only) ----
    {
      float a0 = 0.f;
      #pragma unroll
      for (int i = 0; i < 13; i++){
        if (m0 + i < MM) a0 += w_cur[i]*mv[i];
      }
      a0 += __shfl_xor(a0, 16);
      a0 += __shfl_xor(a0, 32);
      if (kc == 0) bufR[slice*36 + dIn] = a0;
    }
    __syncthreads();   // A

    // ---- stage 2: f = tanh(read @ f_Wr.T + fpre) ----
    float fval;
    {
      const float4* x4 = reinterpret_cast<const float4*>(&bufR[kc*36]);
      float a0=0.f,a1=0.f,a2=0.f,a3=0.f;
      #pragma unroll
      for (int i = 0; i < 8; i++){
        float4 xv = x4[i];
        a0 += xv.x*wf[4*i]; a1 += xv.y*wf[4*i+1]; a2 += xv.z*wf[4*i+2]; a3 += xv.w*wf[4*i+3];
      }
      float s = (a0+a1)+(a2+a3);
      s += __shfl_xor(s, 16);
      s += __shfl_xor(s, 32);
      fval = tanhf(s + fpre_c);
      if (kc == 0){
        bufF[slice*36 + dIn] = fval;
        fAll[row*DD + d] = fval;
      }
    }
    __syncthreads();   // B

    // ---- stage 3: y = ypre + f @ a_Wf.T ----
    {
      const float4* x4 = reinterpret_cast<const float4*>(&bufF[kc*36]);
      float a0=0.f,a1=0.f,a2=0.f,a3=0.f;
      #pragma unroll
      for (int i = 0; i < 8; i++){
        float4 xv = x4[i];
        a0 += xv.x*wa[4*i]; a1 += xv.y*wa[4*i+1]; a2 += xv.z*wa[4*i+2]; a3 += xv.w*wa[4*i+3];
      }
      float s = (a0+a1)+(a2+a3);
      s += __shfl_xor(s, 16);
      s += __shfl_xor(s, 32);
      if (kc == 0) bufY[slice*36 + dIn] = s + ypre_c;
    }
    __syncthreads();   // C

    // ---- stage 4: e = sigmoid(y@e_W.T), a = tanh(y@add_W.T)  (all lanes get full sums) ----
    float e_d, a_d;
    {
      const float4* x4 = reinterpret_cast<const float4*>(&bufY[kc*36]);
      float e0=0.f,e1=0.f,g0=0.f,g1=0.f;
      #pragma unroll
      for (int i = 0; i < 8; i++){
        float4 xv = x4[i];
        e0 += xv.x*we[4*i];   e1 += xv.y*we[4*i+1];
        e0 += xv.z*we[4*i+2]; e1 += xv.w*we[4*i+3];
        g0 += xv.x*wd[4*i];   g1 += xv.y*wd[4*i+1];
        g0 += xv.z*wd[4*i+2]; g1 += xv.w*wd[4*i+3];
      }
      float ep = e0 + e1, ap = g0 + g1;
      ep += __shfl_xor(ep, 16);  ep += __shfl_xor(ep, 32);
      ap += __shfl_xor(ap, 16);  ap += __shfl_xor(ap, 32);
      e_d = sigmoidf_(ep + ebv);
      a_d = tanhf(ap + adbv);
    }

    // ---- stage 5: Mv update (registers only, NO barrier) ----
    #pragma unroll
    for (int i = 0; i < 13; i++){
      if (m0 + i < MM){
        float wv = w_cur[i];
        mv[i] = mv[i]*(1.f - wv*e_d) + wv*a_d;
      }
    }

    // rotate prefetch
    #pragma unroll
    for (int i = 0; i < 13; i++) w_cur[i] = w_nxt[i];
    fpre_c = fpre_n; ypre_c = ypre_n;
  }
}

// ---------------------------------------------------------------------------
// Kernel D: gpre GEMM (unchanged).
// ---------------------------------------------------------------------------
__global__ __launch_bounds__(256) void kGate(
    const float* __restrict__ fAll, const float* __restrict__ Wih,
    const float* __restrict__ bih, const float* __restrict__ bhh,
    float* __restrict__ gpre)
{
  const int jt = blockIdx.x;
  const int rt = blockIdx.y;
  const int tid = threadIdx.x;
  __shared__ float sW[64*129];
  __shared__ float sF[32*129];
  for (int i = tid; i < 64*128; i += 256){
    int jj = i >> 7, k = i & 127;
    sW[jj*129 + k] = Wih[(size_t)(jt*64 + jj)*128 + k];
  }
  for (int i = tid; i < 32*128; i += 256){
    int rr = i >> 7, k = i & 127;
    sF[rr*129 + k] = fAll[(size_t)(rt*32 + rr)*128 + k];
  }
  __syncthreads();
  const int jq = tid & 31, rq = tid >> 5;
  float acc[4][2];
  #pragma unroll
  for (int a = 0; a < 4; a++){ acc[a][0] = 0.f; acc[a][1] = 0.f; }
  for (int k = 0; k < 128; k++){
    float fv[4], wv[2];
    #pragma unroll
    for (int a = 0; a < 4; a++) fv[a] = sF[(rq*4 + a)*129 + k];
    wv[0] = sW[(jq*2 + 0)*129 + k];
    wv[1] = sW[(jq*2 + 1)*129 + k];
    #pragma unroll
    for (int a = 0; a < 4; a++){ acc[a][0] += fv[a]*wv[0]; acc[a][1] += fv[a]*wv[1]; }
  }
  #pragma unroll
  for (int a = 0; a < 4; a++){
    int rowi = rt*32 + rq*4 + a;
    #pragma unroll
    for (int c = 0; c < 2; c++){
      int j = jt*64 + jq*2 + c;
      gpre[(size_t)rowi*512 + j] = acc[a][c] + bih[j] + bhh[j];
    }
  }
}

// ---------------------------------------------------------------------------
// Kernel C (REWRITTEN): LSTM with skip routing. One block/batch, 512 threads.
// 3 barriers/step. Skip reads Hh/Ch[prev[t+1]] prefetched during step t
// (valid because prev[t+1] <= t; the ==t case is served from LDS sh/sc).
// ---------------------------------------------------------------------------
__global__ __launch_bounds__(512, 2) void kLstm(
    const float* __restrict__ gpre, const int* __restrict__ prevA,
    const float* __restrict__ Whh, const float* __restrict__ p_W, const float* __restrict__ p_b,
    float* __restrict__ Hh, float* __restrict__ Ch, float* __restrict__ out)
{
  const int b = blockIdx.x, j = threadIdx.x;
  float whh[128];
  {
    const float4* W4 = reinterpret_cast<const float4*>(&Whh[(size_t)j*128]);
    #pragma unroll
    for (int i = 0; i < 32; i++){
      float4 v = W4[i];
      whh[4*i] = v.x; whh[4*i+1] = v.y; whh[4*i+2] = v.z; whh[4*i+3] = v.w;
    }
  }
  __shared__ __align__(16) float xh[DD];
  __shared__ float sg[512];
  __shared__ float sh[DD];
  __shared__ float sc[DD];
  __shared__ float pred[DD];
  if (j < DD){ sh[j] = 0.f; sc[j] = 0.f; }
  const float pwv = (j < DD) ? p_W[j] : 0.f;
  const float pbv = p_b[0];
  const size_t base = (size_t)b*TT;

  float g_c = gpre[base*512 + j];
  int   pv_c = prevA[base];         // always -1 at t=0
  float preH = 0.f, preC = 0.f;     // prefetched skip values for current t
  __syncthreads();

  for (int t = 0; t < TT; t++){
    const size_t row = base + t;

    // ---- select h_in/c_in, publish h_in to LDS ----
    float cin = 0.f;
    if (j < DD){
      float hin;
      if (pv_c >= 0){
        if (pv_c == t - 1){ hin = sh[j]; cin = sc[j]; }
        else              { hin = preH;  cin = preC;  }
      } else { hin = sh[j]; cin = sc[j]; }
      xh[j] = hin;
    }
    __syncthreads();   // A

    // ---- t+1 prefetches (in flight during gates stage) ----
    float g_n = 0.f; int pv_n = -1;
    if (t + 1 < TT){
      g_n  = gpre[(row + 1)*512 + j];
      pv_n = prevA[row + 1];
    }
    float preH_n = 0.f, preC_n = 0.f;
    if (j < DD && pv_n >= 0 && pv_n < t){   // written at step <= t-1: safe to read now
      preH_n = Hh[(base + pv_n)*DD + j];
      preC_n = Ch[(base + pv_n)*DD + j];
    }

    // ---- gates[j] = gpre + h_in . Whh[j,:] ----
    {
      const float4* x4 = reinterpret_cast<const float4*>(xh);
      float a0=0.f,a1=0.f,a2=0.f,a3=0.f;
      #pragma unroll
      for (int i = 0; i < 32; i++){
        float4 xv = x4[i];
        a0 += xv.x*whh[4*i]; a1 += xv.y*whh[4*i+1]; a2 += xv.z*whh[4*i+2]; a3 += xv.w*whh[4*i+3];
      }
      sg[j] = g_c + (a0+a1)+(a2+a3);
    }
    __syncthreads();   // B

    // ---- cell update ----
    if (j < DD){
      float ig = sg[j], fg = sg[DD + j], gg = sg[2*DD + j], og = sg[3*DD + j];
      float cn = sigmoidf_(fg)*cin + sigmoidf_(ig)*tanhf(gg);
      float hn = sigmoidf_(og)*tanhf(cn);
      sh[j] = hn; sc[j] = cn;
      Hh[row*DD + j] = hn;
      Ch[row*DD + j] = cn;
      pred[j] = hn*pwv;
    }
    __syncthreads();   // C

    // ---- output head ----
    if (j < 64){
      float s = pred[j] + pred[j + 64];
      s += __shfl_down(s, 32); s += __shfl_down(s, 16); s += __shfl_down(s, 8);
      s += __shfl_down(s, 4);  s += __shfl_down(s, 2);  s += __shfl_down(s, 1);
      if (j == 0) out[row] = sigmoidf_(s + pbv);
    }

    g_c = g_n; pv_c = pv_n; preH = preH_n; preC = preC_n;
  }
}

// ---------------------------------------------------------------------------
// Launch.
// ---------------------------------------------------------------------------
extern "C" void kernel_launch(void* const* d_in, const int* in_sizes, int n_in,
                              void* d_out, int out_size, void* d_ws, size_t ws_size,
                              hipStream_t stream) {
  const int*   q     = (const int*)  d_in[0];
  const int*   r     = (const int*)  d_in[1];
  const float* k_emb = (const float*)d_in[2];
  const float* Mk    = (const float*)d_in[3];
  const float* Mv0   = (const float*)d_in[4];
  const float* f_W   = (const float*)d_in[5];
  const float* f_b   = (const float*)d_in[6];
  const float* a_W   = (const float*)d_in[7];
  const float* a_b   = (const float*)d_in[8];
  const float* e_W   = (const float*)d_in[9];
  const float* e_b   = (const float*)d_in[10];
  const float* add_W = (const float*)d_in[11];
  const float* add_b = (const float*)d_in[12];
  const float* Wih   = (const float*)d_in[13];
  const float* Whh   = (const float*)d_in[14];
  const float* bih   = (const float*)d_in[15];
  const float* bhh   = (const float*)d_in[16];
  const float* p_W   = (const float*)d_in[17];
  const float* p_b   = (const float*)d_in[18];
  float* out = (float*)d_out;

  char* ws = (char*)d_ws;
  size_t off = 0;
  auto alloc = [&](size_t bytes) -> char* {
    char* p = ws + off;
    off += (bytes + 255) & ~(size_t)255;
    return p;
  };
  float* wAll  = (float*)alloc((size_t)BB*TT*MM*4);
  float* fpre  = (float*)alloc((size_t)BB*TT*DD*4);
  float* ypre  = (float*)alloc((size_t)BB*TT*DD*4);
  float* fAll  = (float*)alloc((size_t)BB*TT*DD*4);
  float* gpre  = (float*)alloc((size_t)BB*TT*512*4);
  float* Hh    = (float*)alloc((size_t)BB*TT*DD*4);
  float* Ch    = (float*)alloc((size_t)BB*TT*DD*4);
  ull*   keyLo = (ull*)  alloc((size_t)BB*TT*8);
  ull*   keyHi = (ull*)  alloc((size_t)BB*TT*8);
  int*   prevA = (int*)  alloc((size_t)BB*TT*4);
  (void)ws_size; (void)in_sizes; (void)n_in; (void)out_size;

  kPre  <<<dim3(16, 32), 256, 0, stream>>>(q, r, k_emb, Mk, f_W, f_b, a_W, a_b,
                                           wAll, keyLo, keyHi, fpre, ypre);
  kMatch<<<32, 512, 0, stream>>>(keyLo, keyHi, prevA);
  kMem  <<<32, 512, 0, stream>>>(wAll, fpre, ypre, f_W, a_W, e_W, e_b, add_W, add_b,
                                 Mv0, fAll);
  kGate <<<dim3(8, 512), 256, 0, stream>>>(fAll, Wih, bih, bhh, gpre);
  kLstm <<<32, 512, 0, stream>>>(gpre, prevA, Whh, p_W, p_b, Hh, Ch, out);
}